// Round 3
// baseline (647.024 us; speedup 1.0000x reference)
//
#include <hip/hip_runtime.h>

#define NNODES 100000
#define NEDGES 1600000
#define BN_EPS 1e-5f
#define L2_EPS 1e-12f

#define BKT_SHIFT 9
#define BKT_SIZE  512
#define NBKT      196            // ceil(100000/512)
#define CHUNK     8192
#define NBLK_E    196            // ceil(1600000/8192)
#define NSLOT     64             // BN-stats shard count
#define NPB       64             // nodes per layer-block (divides BKT_SIZE)
#define SRCMASK   0x03FFFFFFu    // low 26 bits of packed col = src id

// ---------------------------------------------------------------------------
// Wave-level block exclusive scan (NT threads). Leading barrier protects wsum
// reuse across consecutive calls.
template<int NT>
__device__ __forceinline__ int block_excl_scan(int v, int* wsum) {
    __syncthreads();
    constexpr int NW = NT / 64;
    int incl = v;
#pragma unroll
    for (int off = 1; off < 64; off <<= 1) {
        int t = __shfl_up(incl, off);
        if ((threadIdx.x & 63) >= off) incl += t;
    }
    int wid = threadIdx.x >> 6;
    if ((threadIdx.x & 63) == 63) wsum[wid] = incl;
    __syncthreads();
    if (threadIdx.x < NW) {
        int w = wsum[threadIdx.x];
#pragma unroll
        for (int off = 1; off < NW; off <<= 1) {
            int t = __shfl_up(w, off);
            if ((int)threadIdx.x >= off) w += t;
        }
        wsum[threadIdx.x] = w;             // inclusive wave sums
    }
    __syncthreads();
    int base = wid ? wsum[wid - 1] : 0;
    return base + incl - v;
}

// ---------------------------------------------------------------------------
// Pass 1: per-block bucket histogram (LDS) -> transposed blk_hist. Block 0
// also zeroes the sharded BN stats accumulators.
__global__ void hist_kernel(const int* __restrict__ dst,
                            int* __restrict__ blk_hist_T, float* __restrict__ stats) {
    __shared__ int h[NBKT];
    for (int i = threadIdx.x; i < NBKT; i += blockDim.x) h[i] = 0;
    if (blockIdx.x == 0)
        for (int i = threadIdx.x; i < 3 * NSLOT * 64; i += blockDim.x) stats[i] = 0.0f;
    __syncthreads();
    int base = blockIdx.x * CHUNK;
    int end  = min(base + CHUNK, NEDGES);
    for (int e = base + threadIdx.x * 4; e < end; e += blockDim.x * 4) {
        int4 d = *reinterpret_cast<const int4*>(dst + e);
        atomicAdd(&h[d.x >> BKT_SHIFT], 1);
        atomicAdd(&h[d.y >> BKT_SHIFT], 1);
        atomicAdd(&h[d.z >> BKT_SHIFT], 1);
        atomicAdd(&h[d.w >> BKT_SHIFT], 1);
    }
    __syncthreads();
    for (int i = threadIdx.x; i < NBKT; i += blockDim.x)
        blk_hist_T[i * NBLK_E + blockIdx.x] = h[i];   // [bucket][block]
}

// Per-bucket exclusive scan across blocks + bucket totals as by-product.
__global__ void scan_blocks(const int* __restrict__ blk_hist_T,
                            int* __restrict__ blk_off, int* __restrict__ bucket_total) {
    __shared__ int wsum[4];
    int b = blockIdx.x;
    int i = threadIdx.x;
    int v = (i < NBLK_E) ? blk_hist_T[b * NBLK_E + i] : 0;
    int excl = block_excl_scan<256>(v, wsum);
    if (i < NBLK_E) blk_off[i * NBKT + b] = excl;     // [block][bucket]
    if (i == 255) bucket_total[b] = excl + v;
}

// Pass 2: scatter edges into bucket segments (packed dst_local<<23 | src).
__global__ void bucket_scatter(const int* __restrict__ src, const int* __restrict__ dst,
                               const int* __restrict__ blk_off, const int* __restrict__ bucket_total,
                               unsigned int* __restrict__ staged) {
    __shared__ int cur[NBKT];
    __shared__ int wsum[8];
    int v = (threadIdx.x < NBKT) ? bucket_total[threadIdx.x] : 0;
    int bbase = block_excl_scan<512>(v, wsum);
    if (threadIdx.x < NBKT)
        cur[threadIdx.x] = bbase + blk_off[blockIdx.x * NBKT + threadIdx.x];
    __syncthreads();
    int base = blockIdx.x * CHUNK;
    int end  = min(base + CHUNK, NEDGES);
    for (int e = base + threadIdx.x * 4; e < end; e += blockDim.x * 4) {
        int4 d = *reinterpret_cast<const int4*>(dst + e);
        int4 s = *reinterpret_cast<const int4*>(src + e);
        int p0 = atomicAdd(&cur[d.x >> BKT_SHIFT], 1);
        staged[p0] = ((unsigned)(d.x & (BKT_SIZE - 1)) << 23) | (unsigned)s.x;
        int p1 = atomicAdd(&cur[d.y >> BKT_SHIFT], 1);
        staged[p1] = ((unsigned)(d.y & (BKT_SIZE - 1)) << 23) | (unsigned)s.y;
        int p2 = atomicAdd(&cur[d.z >> BKT_SHIFT], 1);
        staged[p2] = ((unsigned)(d.z & (BKT_SIZE - 1)) << 23) | (unsigned)s.z;
        int p3 = atomicAdd(&cur[d.w >> BKT_SHIFT], 1);
        staged[p3] = ((unsigned)(d.w & (BKT_SIZE - 1)) << 23) | (unsigned)s.w;
    }
}

// Pass 3: one block per bucket -> exact CSR. col entries carry the node-local
// id (within a 64-node layer block) in the top 6 bits: (l & 63) << 26 | src.
__global__ void csr_finalize(const unsigned int* __restrict__ staged,
                             const int* __restrict__ bucket_total,
                             int* __restrict__ row_ptr, unsigned int* __restrict__ col) {
    __shared__ int nh[BKT_SIZE];
    __shared__ int cur[BKT_SIZE];
    __shared__ int wsum[8];
    __shared__ int sBeg, sEnd;
    int b = blockIdx.x;

    nh[threadIdx.x] = 0;                      // covered by scan's leading barrier
    int v = (threadIdx.x < NBKT) ? bucket_total[threadIdx.x] : 0;
    int excl = block_excl_scan<512>(v, wsum);
    if (threadIdx.x == b) { sBeg = excl; sEnd = excl + v; }
    __syncthreads();
    int beg = sBeg, end = sEnd;

    for (int e = beg + threadIdx.x; e < end; e += blockDim.x)
        atomicAdd(&nh[staged[e] >> 23], 1);
    __syncthreads();

    int hv = nh[threadIdx.x];
    int hexcl = block_excl_scan<512>(hv, wsum);

    int node = b * BKT_SIZE + threadIdx.x;
    if (node < NNODES) row_ptr[node] = beg + hexcl;
    if (b == 0 && threadIdx.x == 0) row_ptr[NNODES] = NEDGES;
    cur[threadIdx.x] = hexcl;
    __syncthreads();

    for (int e = beg + threadIdx.x; e < end; e += blockDim.x) {
        unsigned pk = staged[e];
        int l = (int)(pk >> 23);
        int p = atomicAdd(&cur[l], 1);          // LDS atomic only
        col[beg + p] = ((unsigned)(l & (NPB - 1)) << 26) | (pk & 0x7FFFFF);
    }
}

// ---------------------------------------------------------------------------
// Vector row load: float4 chunks, then float2, then scalar.
template<int CI>
__device__ __forceinline__ void load_row(const float* __restrict__ p, float* r) {
    constexpr int N4 = CI / 4;
#pragma unroll
    for (int i = 0; i < N4; i++) {
        float4 v = ((const float4*)p)[i];
        r[4*i] = v.x; r[4*i+1] = v.y; r[4*i+2] = v.z; r[4*i+3] = v.w;
    }
    if constexpr ((CI % 4) >= 2) {
        float2 v = ((const float2*)(p + 4 * N4))[0];
        r[4*N4] = v.x; r[4*N4+1] = v.y;
    }
    if constexpr ((CI % 2) == 1) r[CI - 1] = p[CI - 1];
}

// ---------------------------------------------------------------------------
// Two-phase fused layer. Phase A: edge-parallel gather + LDS-atomic
// accumulation per destination (no butterfly, no divergence, coalesced col).
// Phase B: node-parallel linear + L2-norm + ReLU + BN-stats. BN affine of the
// previous layer is applied post-aggregation (linearity).
template<int CI, int SI, int CO, int SO, bool IN_AFFINE, bool DO_STATS>
__global__ void layer_kernel(const int* __restrict__ row_ptr, const unsigned int* __restrict__ col,
                             const float* __restrict__ h,
                             const float* __restrict__ ssum_in, const float* __restrict__ ssq_in,
                             const float* __restrict__ g_in, const float* __restrict__ b_in,
                             const float* __restrict__ wl, const float* __restrict__ bl,
                             const float* __restrict__ wr,
                             float* __restrict__ y,
                             float* __restrict__ stat_sum, float* __restrict__ stat_sq) {
    constexpr int CIp = CI + 1;              // padded stride (bank spread)
    constexpr int OPT = (CO + 3) / 4;        // outputs per thread (4 thr/node)

    __shared__ float acc[NPB * CIp];
    __shared__ float sWl[CO * CIp];
    __shared__ float sWr[CO * CIp];
    __shared__ float sBl[CO];
    __shared__ float sSc[CI];
    __shared__ float sSh[CI];
    __shared__ int   sRP[NPB + 1];
    __shared__ float sSumR[CI];
    __shared__ float sSqR[CI];
    __shared__ float red_sum[CO];
    __shared__ float red_sq[CO];

    int tid = threadIdx.x;
    for (int i = tid; i < CO * CI; i += 256) {
        int o = i / CI, c = i - o * CI;
        sWl[o * CIp + c] = wl[i];
        sWr[o * CIp + c] = wr[i];
    }
    if (tid < CO) {
        sBl[tid] = bl[tid];
        if (DO_STATS) { red_sum[tid] = 0.0f; red_sq[tid] = 0.0f; }
    }
    for (int i = tid; i < NPB * CIp; i += 256) acc[i] = 0.0f;
    int first = blockIdx.x * NPB;
    if (tid <= NPB) sRP[tid] = row_ptr[min(first + tid, NNODES)];
    if (IN_AFFINE && tid < CI) { sSumR[tid] = 0.0f; sSqR[tid] = 0.0f; }
    __syncthreads();
    if (IN_AFFINE) {
        int c = tid & 31, sl = tid >> 5;     // 8 slices over NSLOT shards
        if (c < CI) {
            float ps = 0.0f, pq = 0.0f;
#pragma unroll
            for (int s = sl; s < NSLOT; s += 8) {
                ps += ssum_in[s * 64 + c];
                pq += ssq_in[s * 64 + c];
            }
            atomicAdd(&sSumR[c], ps);
            atomicAdd(&sSqR[c], pq);
        }
        __syncthreads();
        if (tid < CI) {
            float m  = sSumR[tid] * (1.0f / NNODES);
            float vv = sSqR[tid] * (1.0f / NNODES) - m * m;
            float s  = g_in[tid] / sqrtf(vv + BN_EPS);
            sSc[tid] = s;
            sSh[tid] = b_in[tid] - m * s;
        }
        __syncthreads();
    }

    // ---- Phase A: edge-parallel accumulate ----
    int ebeg = sRP[0], eend = sRP[NPB];
    int e = ebeg + tid;
    for (; e + 3 * 256 < eend; e += 4 * 256) {
        unsigned v0 = col[e], v1 = col[e + 256], v2 = col[e + 512], v3 = col[e + 768];
        float r0[CI], r1[CI], r2[CI], r3[CI];
        load_row<CI>(h + (long)(v0 & SRCMASK) * SI, r0);
        load_row<CI>(h + (long)(v1 & SRCMASK) * SI, r1);
        load_row<CI>(h + (long)(v2 & SRCMASK) * SI, r2);
        load_row<CI>(h + (long)(v3 & SRCMASK) * SI, r3);
        int d0 = (int)(v0 >> 26) * CIp, d1 = (int)(v1 >> 26) * CIp;
        int d2 = (int)(v2 >> 26) * CIp, d3 = (int)(v3 >> 26) * CIp;
#pragma unroll
        for (int c = 0; c < CI; c++) atomicAdd(&acc[d0 + c], r0[c]);
#pragma unroll
        for (int c = 0; c < CI; c++) atomicAdd(&acc[d1 + c], r1[c]);
#pragma unroll
        for (int c = 0; c < CI; c++) atomicAdd(&acc[d2 + c], r2[c]);
#pragma unroll
        for (int c = 0; c < CI; c++) atomicAdd(&acc[d3 + c], r3[c]);
    }
    for (; e < eend; e += 256) {
        unsigned v0 = col[e];
        float r0[CI];
        load_row<CI>(h + (long)(v0 & SRCMASK) * SI, r0);
        int d0 = (int)(v0 >> 26) * CIp;
#pragma unroll
        for (int c = 0; c < CI; c++) atomicAdd(&acc[d0 + c], r0[c]);
    }
    __syncthreads();

    // ---- Phase B: node-parallel epilogue (4 threads per node) ----
    int nl = tid >> 2, t = tid & 3;
    int node = first + nl;
    bool valid = node < NNODES;

    float outv[OPT];
    float nrm2 = 0.0f;
    if (valid) {
        int deg = sRP[nl + 1] - sRP[nl];
        float ic = 1.0f / fmaxf((float)deg, 1.0f);
        float a[CI], xin[CI];
        load_row<CI>(h + (long)node * SI, xin);
#pragma unroll
        for (int c = 0; c < CI; c++) {
            float av = acc[nl * CIp + c] * ic;
            float xv = xin[c];
            if (IN_AFFINE) {
                av = av * sSc[c] + sSh[c];
                xv = xv * sSc[c] + sSh[c];
            }
            a[c] = av;
            xin[c] = xv;
        }
#pragma unroll
        for (int k = 0; k < OPT; k++) {
            int o = t * OPT + k;
            float v = 0.0f;
            if (o < CO) {
                v = sBl[o];
#pragma unroll
                for (int c = 0; c < CI; c++)
                    v += sWl[o * CIp + c] * a[c] + sWr[o * CIp + c] * xin[c];
            }
            outv[k] = v;
            nrm2 += v * v;
        }
    }
    nrm2 += __shfl_xor(nrm2, 1);             // quad-local reduce (same node)
    nrm2 += __shfl_xor(nrm2, 2);

    if (valid) {
        float inv_nrm = 1.0f / fmaxf(sqrtf(nrm2), L2_EPS);
        float st[OPT];
#pragma unroll
        for (int k = 0; k < OPT; k++) st[k] = fmaxf(outv[k] * inv_nrm, 0.0f);
        float* yp = y + (long)node * SO + t * OPT;
#pragma unroll
        for (int k = 0; k < OPT; k++) {
            int o = t * OPT + k;
            if (o < CO) {
                yp[k] = st[k];
                if (DO_STATS) {
                    atomicAdd(&red_sum[o], st[k]);
                    atomicAdd(&red_sq[o], st[k] * st[k]);
                }
            }
        }
    }

    if (DO_STATS) {
        __syncthreads();
        if (tid < CO) {
            int slot = blockIdx.x & (NSLOT - 1);
            atomicAdd(&stat_sum[slot * 64 + tid], red_sum[tid]);
            atomicAdd(&stat_sq [slot * 64 + tid], red_sq[tid]);
        }
    }
}

// ---------------------------------------------------------------------------
extern "C" void kernel_launch(void* const* d_in, const int* in_sizes, int n_in,
                              void* d_out, int out_size, void* d_ws, size_t ws_size,
                              hipStream_t stream) {
    const float* x   = (const float*)d_in[0];
    const int*   ei  = (const int*)d_in[1];
    const int*   src = ei;
    const int*   dst = ei + NEDGES;

    const float* w1l = (const float*)d_in[2];
    const float* b1l = (const float*)d_in[3];
    const float* w1r = (const float*)d_in[4];
    const float* w2l = (const float*)d_in[5];
    const float* b2l = (const float*)d_in[6];
    const float* w2r = (const float*)d_in[7];
    const float* w3l = (const float*)d_in[8];
    const float* b3l = (const float*)d_in[9];
    const float* w3r = (const float*)d_in[10];
    const float* w4l = (const float*)d_in[11];
    const float* b4l = (const float*)d_in[12];
    const float* w4r = (const float*)d_in[13];
    const float* g1  = (const float*)d_in[14];
    const float* be1 = (const float*)d_in[15];
    const float* g2  = (const float*)d_in[16];
    const float* be2 = (const float*)d_in[17];
    const float* g3  = (const float*)d_in[18];
    const float* be3 = (const float*)d_in[19];

    char* w = (char*)d_ws;
    int* blk_hist     = (int*)w;  w += NBLK_E * NBKT * 4;
    int* blk_off      = (int*)w;  w += NBLK_E * NBKT * 4;
    int* bucket_total = (int*)w;  w += 256 * 4;
    int* row_ptr      = (int*)w;  w += (NNODES + 8) * 4;
    unsigned int* col = (unsigned int*)w; w += NEDGES * 4;
    float* hA         = (float*)w; w += NNODES * 16 * 4;
    float* hB         = (float*)w; w += NNODES * 16 * 4;   // aliased by staged
    float* stats      = (float*)w; w += 3 * NSLOT * 64 * 4;
    unsigned int* staged = (unsigned int*)hB;  // dead before hB is written

    float* ssum1 = stats + 0 * NSLOT * 64, *ssq1 = ssum1 + 32;
    float* ssum2 = stats + 1 * NSLOT * 64, *ssq2 = ssum2 + 32;
    float* ssum3 = stats + 2 * NSLOT * 64, *ssq3 = ssum3 + 32;

    // atomic-free CSR build (LDS atomics only), 4 launches
    hist_kernel   <<<NBLK_E, 512, 0, stream>>>(dst, blk_hist, stats);
    scan_blocks   <<<NBKT, 256, 0, stream>>>(blk_hist, blk_off, bucket_total);
    bucket_scatter<<<NBLK_E, 512, 0, stream>>>(src, dst, blk_off, bucket_total, staged);
    csr_finalize  <<<NBKT, 512, 0, stream>>>(staged, bucket_total, row_ptr, col);

    const int NLBLK = (NNODES + NPB - 1) / NPB;   // 1563

    // layer 1: 4 -> 6 (stride 4 -> 8), +stats
    layer_kernel<4, 4, 6, 8, false, true><<<NLBLK, 256, 0, stream>>>(
        row_ptr, col, x, nullptr, nullptr, nullptr, nullptr,
        w1l, b1l, w1r, hA, ssum1, ssq1);

    // layer 2: 6 -> 8 (stride 8 -> 8), BN1 derived in-block, +stats
    layer_kernel<6, 8, 8, 8, true, true><<<NLBLK, 256, 0, stream>>>(
        row_ptr, col, hA, ssum1, ssq1, g1, be1,
        w2l, b2l, w2r, hB, ssum2, ssq2);

    // layer 3: 8 -> 16 (stride 8 -> 16), BN2 derived, +stats
    layer_kernel<8, 8, 16, 16, true, true><<<NLBLK, 256, 0, stream>>>(
        row_ptr, col, hB, ssum2, ssq2, g2, be2,
        w3l, b3l, w3r, hA, ssum3, ssq3);

    // layer 4: 16 -> 32 (stride 16 -> 32), BN3 derived, ReLU -> d_out
    layer_kernel<16, 16, 32, 32, true, false><<<NLBLK, 256, 0, stream>>>(
        row_ptr, col, hA, ssum3, ssq3, g3, be3,
        w4l, b4l, w4r, (float*)d_out, nullptr, nullptr);
}

// Round 4
// 550.959 us; speedup vs baseline: 1.1744x; 1.1744x over previous
//
#include <hip/hip_runtime.h>

#define NNODES 100000
#define NEDGES 1600000
#define BN_EPS 1e-5f
#define L2_EPS 1e-12f

#define BKT_SHIFT 9
#define BKT_SIZE  512
#define NBKT      196            // ceil(100000/512)
#define CHUNK     8192
#define NBLK_E    196            // ceil(1600000/8192)
#define NSLOT     64             // BN-stats shard count
#define NPB       64             // nodes per layer-block (divides BKT_SIZE)
#define SRCMASK   0x03FFFFFFu    // low 26 bits of packed col = src id

// ---------------------------------------------------------------------------
// Wave-level block exclusive scan (NT threads). Leading barrier protects wsum
// reuse across consecutive calls.
template<int NT>
__device__ __forceinline__ int block_excl_scan(int v, int* wsum) {
    __syncthreads();
    constexpr int NW = NT / 64;
    int incl = v;
#pragma unroll
    for (int off = 1; off < 64; off <<= 1) {
        int t = __shfl_up(incl, off);
        if ((threadIdx.x & 63) >= off) incl += t;
    }
    int wid = threadIdx.x >> 6;
    if ((threadIdx.x & 63) == 63) wsum[wid] = incl;
    __syncthreads();
    if (threadIdx.x < NW) {
        int w = wsum[threadIdx.x];
#pragma unroll
        for (int off = 1; off < NW; off <<= 1) {
            int t = __shfl_up(w, off);
            if ((int)threadIdx.x >= off) w += t;
        }
        wsum[threadIdx.x] = w;             // inclusive wave sums
    }
    __syncthreads();
    int base = wid ? wsum[wid - 1] : 0;
    return base + incl - v;
}

// ---------------------------------------------------------------------------
// Pass 1: per-block bucket histogram (LDS) -> transposed blk_hist. Block 0
// also zeroes the sharded BN stats accumulators.
__global__ void hist_kernel(const int* __restrict__ dst,
                            int* __restrict__ blk_hist_T, float* __restrict__ stats) {
    __shared__ int h[NBKT];
    for (int i = threadIdx.x; i < NBKT; i += blockDim.x) h[i] = 0;
    if (blockIdx.x == 0)
        for (int i = threadIdx.x; i < 3 * NSLOT * 64; i += blockDim.x) stats[i] = 0.0f;
    __syncthreads();
    int base = blockIdx.x * CHUNK;
    int end  = min(base + CHUNK, NEDGES);
    for (int e = base + threadIdx.x * 4; e < end; e += blockDim.x * 4) {
        int4 d = *reinterpret_cast<const int4*>(dst + e);
        atomicAdd(&h[d.x >> BKT_SHIFT], 1);
        atomicAdd(&h[d.y >> BKT_SHIFT], 1);
        atomicAdd(&h[d.z >> BKT_SHIFT], 1);
        atomicAdd(&h[d.w >> BKT_SHIFT], 1);
    }
    __syncthreads();
    for (int i = threadIdx.x; i < NBKT; i += blockDim.x)
        blk_hist_T[i * NBLK_E + blockIdx.x] = h[i];   // [bucket][block]
}

// Per-bucket exclusive scan across blocks + bucket totals as by-product.
__global__ void scan_blocks(const int* __restrict__ blk_hist_T,
                            int* __restrict__ blk_off, int* __restrict__ bucket_total) {
    __shared__ int wsum[4];
    int b = blockIdx.x;
    int i = threadIdx.x;
    int v = (i < NBLK_E) ? blk_hist_T[b * NBLK_E + i] : 0;
    int excl = block_excl_scan<256>(v, wsum);
    if (i < NBLK_E) blk_off[i * NBKT + b] = excl;     // [block][bucket]
    if (i == 255) bucket_total[b] = excl + v;
}

// Pass 2: scatter edges into bucket segments (packed dst_local<<23 | src).
__global__ void bucket_scatter(const int* __restrict__ src, const int* __restrict__ dst,
                               const int* __restrict__ blk_off, const int* __restrict__ bucket_total,
                               unsigned int* __restrict__ staged) {
    __shared__ int cur[NBKT];
    __shared__ int wsum[8];
    int v = (threadIdx.x < NBKT) ? bucket_total[threadIdx.x] : 0;
    int bbase = block_excl_scan<512>(v, wsum);
    if (threadIdx.x < NBKT)
        cur[threadIdx.x] = bbase + blk_off[blockIdx.x * NBKT + threadIdx.x];
    __syncthreads();
    int base = blockIdx.x * CHUNK;
    int end  = min(base + CHUNK, NEDGES);
    for (int e = base + threadIdx.x * 4; e < end; e += blockDim.x * 4) {
        int4 d = *reinterpret_cast<const int4*>(dst + e);
        int4 s = *reinterpret_cast<const int4*>(src + e);
        int p0 = atomicAdd(&cur[d.x >> BKT_SHIFT], 1);
        staged[p0] = ((unsigned)(d.x & (BKT_SIZE - 1)) << 23) | (unsigned)s.x;
        int p1 = atomicAdd(&cur[d.y >> BKT_SHIFT], 1);
        staged[p1] = ((unsigned)(d.y & (BKT_SIZE - 1)) << 23) | (unsigned)s.y;
        int p2 = atomicAdd(&cur[d.z >> BKT_SHIFT], 1);
        staged[p2] = ((unsigned)(d.z & (BKT_SIZE - 1)) << 23) | (unsigned)s.z;
        int p3 = atomicAdd(&cur[d.w >> BKT_SHIFT], 1);
        staged[p3] = ((unsigned)(d.w & (BKT_SIZE - 1)) << 23) | (unsigned)s.w;
    }
}

// Pass 3: one block per bucket -> exact CSR. col entries carry the node-local
// id (within a 64-node layer block) in the top 6 bits: (l & 63) << 26 | src.
__global__ void csr_finalize(const unsigned int* __restrict__ staged,
                             const int* __restrict__ bucket_total,
                             int* __restrict__ row_ptr, unsigned int* __restrict__ col) {
    __shared__ int nh[BKT_SIZE];
    __shared__ int cur[BKT_SIZE];
    __shared__ int wsum[8];
    __shared__ int sBeg, sEnd;
    int b = blockIdx.x;

    nh[threadIdx.x] = 0;                      // covered by scan's leading barrier
    int v = (threadIdx.x < NBKT) ? bucket_total[threadIdx.x] : 0;
    int excl = block_excl_scan<512>(v, wsum);
    if (threadIdx.x == b) { sBeg = excl; sEnd = excl + v; }
    __syncthreads();
    int beg = sBeg, end = sEnd;

    for (int e = beg + threadIdx.x; e < end; e += blockDim.x)
        atomicAdd(&nh[staged[e] >> 23], 1);
    __syncthreads();

    int hv = nh[threadIdx.x];
    int hexcl = block_excl_scan<512>(hv, wsum);

    int node = b * BKT_SIZE + threadIdx.x;
    if (node < NNODES) row_ptr[node] = beg + hexcl;
    if (b == 0 && threadIdx.x == 0) row_ptr[NNODES] = NEDGES;
    cur[threadIdx.x] = hexcl;
    __syncthreads();

    for (int e = beg + threadIdx.x; e < end; e += blockDim.x) {
        unsigned pk = staged[e];
        int l = (int)(pk >> 23);
        int p = atomicAdd(&cur[l], 1);          // LDS atomic only
        col[beg + p] = ((unsigned)(l & (NPB - 1)) << 26) | (pk & 0x7FFFFF);
    }
}

// ---------------------------------------------------------------------------
// Vector row load: float4 chunks, then float2, then scalar.
template<int CI>
__device__ __forceinline__ void load_row(const float* __restrict__ p, float* r) {
    constexpr int N4 = CI / 4;
#pragma unroll
    for (int i = 0; i < N4; i++) {
        float4 v = ((const float4*)p)[i];
        r[4*i] = v.x; r[4*i+1] = v.y; r[4*i+2] = v.z; r[4*i+3] = v.w;
    }
    if constexpr ((CI % 4) >= 2) {
        float2 v = ((const float2*)(p + 4 * N4))[0];
        r[4*N4] = v.x; r[4*N4+1] = v.y;
    }
    if constexpr ((CI % 2) == 1) r[CI - 1] = p[CI - 1];
}

// ---------------------------------------------------------------------------
// Two-phase fused layer, register-lean.
// Phase A (edge x chunk parallel): thread = (edge slot, float4 chunk).
//   One float4 + one col word per in-flight edge -> no spill. ds_add_f32
//   accumulate into padded acc[NPB][CIL+1].
// Phase B (node parallel, 8 thr/node): linear + L2 norm + ReLU + BN stats.
// CIL >= CI (multiple of 4): for CI=6 we accumulate 8 channels; the 2 garbage
// channels of the stride-8 rows are never read in Phase B (linearity).
template<int CI, int CIL, int SI, int CO, int SO, bool IN_AFFINE, bool DO_STATS>
__global__ __launch_bounds__(512, 4)
void layer_kernel(const int* __restrict__ row_ptr, const unsigned int* __restrict__ col,
                  const float* __restrict__ h,
                  const float* __restrict__ ssum_in, const float* __restrict__ ssq_in,
                  const float* __restrict__ g_in, const float* __restrict__ b_in,
                  const float* __restrict__ wl, const float* __restrict__ bl,
                  const float* __restrict__ wr,
                  float* __restrict__ y,
                  float* __restrict__ stat_sum, float* __restrict__ stat_sq) {
    constexpr int CIp  = CI + 1;             // padded weight stride
    constexpr int CILp = CIL + 1;            // padded acc stride
    constexpr int NCH  = CIL / 4;            // float4 chunks per edge
    constexpr int EPI  = 512 / NCH;          // edge slots per iteration
    constexpr int TPN  = 512 / NPB;          // 8 threads per node
    constexpr int OPT  = (CO + TPN - 1) / TPN;

    __shared__ float acc[NPB * CILp];
    __shared__ float sWl[CO * CIp];
    __shared__ float sWr[CO * CIp];
    __shared__ float sBl[CO];
    __shared__ float sSc[CI];
    __shared__ float sSh[CI];
    __shared__ int   sRP[NPB + 1];
    __shared__ float sSumR[CI];
    __shared__ float sSqR[CI];
    __shared__ float red_sum[CO];
    __shared__ float red_sq[CO];

    int tid = threadIdx.x;
    for (int i = tid; i < CO * CI; i += 512) {
        int o = i / CI, c = i - o * CI;
        sWl[o * CIp + c] = wl[i];
        sWr[o * CIp + c] = wr[i];
    }
    if (tid < CO) {
        sBl[tid] = bl[tid];
        if (DO_STATS) { red_sum[tid] = 0.0f; red_sq[tid] = 0.0f; }
    }
    for (int i = tid; i < NPB * CILp; i += 512) acc[i] = 0.0f;
    int first = blockIdx.x * NPB;
    if (tid <= NPB) sRP[tid] = row_ptr[min(first + tid, NNODES)];
    if (IN_AFFINE && tid < CI) { sSumR[tid] = 0.0f; sSqR[tid] = 0.0f; }
    __syncthreads();
    if (IN_AFFINE) {
        int c = tid & 31, sl = tid >> 5;     // 16 slices over NSLOT shards
        if (c < CI) {
            float ps = 0.0f, pq = 0.0f;
#pragma unroll
            for (int s = sl; s < NSLOT; s += 16) {
                ps += ssum_in[s * 64 + c];
                pq += ssq_in[s * 64 + c];
            }
            atomicAdd(&sSumR[c], ps);
            atomicAdd(&sSqR[c], pq);
        }
        __syncthreads();
        if (tid < CI) {
            float m  = sSumR[tid] * (1.0f / NNODES);
            float vv = sSqR[tid] * (1.0f / NNODES) - m * m;
            float s  = g_in[tid] / sqrtf(vv + BN_EPS);
            sSc[tid] = s;
            sSh[tid] = b_in[tid] - m * s;
        }
        __syncthreads();
    }

    // ---- Phase A: edge x chunk parallel accumulate ----
    int ebeg = sRP[0], eend = sRP[NPB];
    int ch4 = (tid & (NCH - 1)) * 4;         // channel offset of my chunk
    int e   = ebeg + tid / NCH;              // my edge slot

    // 4 edges in flight (per-thread state: 4 x (u32 + float4) ~ 24 VGPR)
    for (; e + 3 * EPI < eend; e += 4 * EPI) {
        unsigned v0 = col[e], v1 = col[e + EPI], v2 = col[e + 2 * EPI], v3 = col[e + 3 * EPI];
        float4 r0 = *(const float4*)(h + (long)(v0 & SRCMASK) * SI + ch4);
        float4 r1 = *(const float4*)(h + (long)(v1 & SRCMASK) * SI + ch4);
        float4 r2 = *(const float4*)(h + (long)(v2 & SRCMASK) * SI + ch4);
        float4 r3 = *(const float4*)(h + (long)(v3 & SRCMASK) * SI + ch4);
        int d0 = (int)(v0 >> 26) * CILp + ch4;
        int d1 = (int)(v1 >> 26) * CILp + ch4;
        int d2 = (int)(v2 >> 26) * CILp + ch4;
        int d3 = (int)(v3 >> 26) * CILp + ch4;
        atomicAdd(&acc[d0 + 0], r0.x); atomicAdd(&acc[d0 + 1], r0.y);
        atomicAdd(&acc[d0 + 2], r0.z); atomicAdd(&acc[d0 + 3], r0.w);
        atomicAdd(&acc[d1 + 0], r1.x); atomicAdd(&acc[d1 + 1], r1.y);
        atomicAdd(&acc[d1 + 2], r1.z); atomicAdd(&acc[d1 + 3], r1.w);
        atomicAdd(&acc[d2 + 0], r2.x); atomicAdd(&acc[d2 + 1], r2.y);
        atomicAdd(&acc[d2 + 2], r2.z); atomicAdd(&acc[d2 + 3], r2.w);
        atomicAdd(&acc[d3 + 0], r3.x); atomicAdd(&acc[d3 + 1], r3.y);
        atomicAdd(&acc[d3 + 2], r3.z); atomicAdd(&acc[d3 + 3], r3.w);
    }
    // 2 in flight
    for (; e + EPI < eend; e += 2 * EPI) {
        unsigned v0 = col[e], v1 = col[e + EPI];
        float4 r0 = *(const float4*)(h + (long)(v0 & SRCMASK) * SI + ch4);
        float4 r1 = *(const float4*)(h + (long)(v1 & SRCMASK) * SI + ch4);
        int d0 = (int)(v0 >> 26) * CILp + ch4;
        int d1 = (int)(v1 >> 26) * CILp + ch4;
        atomicAdd(&acc[d0 + 0], r0.x); atomicAdd(&acc[d0 + 1], r0.y);
        atomicAdd(&acc[d0 + 2], r0.z); atomicAdd(&acc[d0 + 3], r0.w);
        atomicAdd(&acc[d1 + 0], r1.x); atomicAdd(&acc[d1 + 1], r1.y);
        atomicAdd(&acc[d1 + 2], r1.z); atomicAdd(&acc[d1 + 3], r1.w);
    }
    if (e < eend) {
        unsigned v0 = col[e];
        float4 r0 = *(const float4*)(h + (long)(v0 & SRCMASK) * SI + ch4);
        int d0 = (int)(v0 >> 26) * CILp + ch4;
        atomicAdd(&acc[d0 + 0], r0.x); atomicAdd(&acc[d0 + 1], r0.y);
        atomicAdd(&acc[d0 + 2], r0.z); atomicAdd(&acc[d0 + 3], r0.w);
    }
    __syncthreads();

    // ---- Phase B: node-parallel epilogue (8 threads per node) ----
    int nl = tid / TPN, t = tid & (TPN - 1);
    int node = first + nl;
    bool valid = node < NNODES;

    float outv[OPT];
    float nrm2 = 0.0f;
    if (valid) {
        int deg = sRP[nl + 1] - sRP[nl];
        float ic = 1.0f / fmaxf((float)deg, 1.0f);
        float a[CI], xin[CI];
        load_row<CI>(h + (long)node * SI, xin);
#pragma unroll
        for (int c = 0; c < CI; c++) {
            float av = acc[nl * CILp + c] * ic;
            float xv = xin[c];
            if (IN_AFFINE) {
                av = av * sSc[c] + sSh[c];
                xv = xv * sSc[c] + sSh[c];
            }
            a[c] = av;
            xin[c] = xv;
        }
#pragma unroll
        for (int k = 0; k < OPT; k++) {
            int o = t * OPT + k;
            float v = 0.0f;
            if (o < CO) {
                v = sBl[o];
#pragma unroll
                for (int c = 0; c < CI; c++)
                    v += sWl[o * CIp + c] * a[c] + sWr[o * CIp + c] * xin[c];
            }
            outv[k] = v;
            nrm2 += v * v;
        }
    }
    nrm2 += __shfl_xor(nrm2, 1);             // 8-lane group = one node
    nrm2 += __shfl_xor(nrm2, 2);
    nrm2 += __shfl_xor(nrm2, 4);

    if (valid) {
        float inv_nrm = 1.0f / fmaxf(sqrtf(nrm2), L2_EPS);
#pragma unroll
        for (int k = 0; k < OPT; k++) {
            int o = t * OPT + k;
            if (o < CO) {
                float v = fmaxf(outv[k] * inv_nrm, 0.0f);   // L2 norm + ReLU
                y[(long)node * SO + o] = v;
                if (DO_STATS) {
                    atomicAdd(&red_sum[o], v);
                    atomicAdd(&red_sq[o], v * v);
                }
            }
        }
    }

    if (DO_STATS) {
        __syncthreads();
        if (tid < CO) {
            int slot = blockIdx.x & (NSLOT - 1);
            atomicAdd(&stat_sum[slot * 64 + tid], red_sum[tid]);
            atomicAdd(&stat_sq [slot * 64 + tid], red_sq[tid]);
        }
    }
}

// ---------------------------------------------------------------------------
extern "C" void kernel_launch(void* const* d_in, const int* in_sizes, int n_in,
                              void* d_out, int out_size, void* d_ws, size_t ws_size,
                              hipStream_t stream) {
    const float* x   = (const float*)d_in[0];
    const int*   ei  = (const int*)d_in[1];
    const int*   src = ei;
    const int*   dst = ei + NEDGES;

    const float* w1l = (const float*)d_in[2];
    const float* b1l = (const float*)d_in[3];
    const float* w1r = (const float*)d_in[4];
    const float* w2l = (const float*)d_in[5];
    const float* b2l = (const float*)d_in[6];
    const float* w2r = (const float*)d_in[7];
    const float* w3l = (const float*)d_in[8];
    const float* b3l = (const float*)d_in[9];
    const float* w3r = (const float*)d_in[10];
    const float* w4l = (const float*)d_in[11];
    const float* b4l = (const float*)d_in[12];
    const float* w4r = (const float*)d_in[13];
    const float* g1  = (const float*)d_in[14];
    const float* be1 = (const float*)d_in[15];
    const float* g2  = (const float*)d_in[16];
    const float* be2 = (const float*)d_in[17];
    const float* g3  = (const float*)d_in[18];
    const float* be3 = (const float*)d_in[19];

    char* w = (char*)d_ws;
    int* blk_hist     = (int*)w;  w += NBLK_E * NBKT * 4;
    int* blk_off      = (int*)w;  w += NBLK_E * NBKT * 4;
    int* bucket_total = (int*)w;  w += 256 * 4;
    int* row_ptr      = (int*)w;  w += (NNODES + 8) * 4;
    unsigned int* col = (unsigned int*)w; w += NEDGES * 4;
    float* hA         = (float*)w; w += NNODES * 16 * 4;
    float* hB         = (float*)w; w += NNODES * 16 * 4;   // aliased by staged
    float* stats      = (float*)w; w += 3 * NSLOT * 64 * 4;
    unsigned int* staged = (unsigned int*)hB;  // dead before hB is written

    float* ssum1 = stats + 0 * NSLOT * 64, *ssq1 = ssum1 + 32;
    float* ssum2 = stats + 1 * NSLOT * 64, *ssq2 = ssum2 + 32;
    float* ssum3 = stats + 2 * NSLOT * 64, *ssq3 = ssum3 + 32;

    // atomic-free CSR build (LDS atomics only), 4 launches
    hist_kernel   <<<NBLK_E, 512, 0, stream>>>(dst, blk_hist, stats);
    scan_blocks   <<<NBKT, 256, 0, stream>>>(blk_hist, blk_off, bucket_total);
    bucket_scatter<<<NBLK_E, 512, 0, stream>>>(src, dst, blk_off, bucket_total, staged);
    csr_finalize  <<<NBKT, 512, 0, stream>>>(staged, bucket_total, row_ptr, col);

    const int NLBLK = (NNODES + NPB - 1) / NPB;   // 1563

    // layer 1: 4 -> 6 (stride 4 -> 8), +stats
    layer_kernel<4, 4, 4, 6, 8, false, true><<<NLBLK, 512, 0, stream>>>(
        row_ptr, col, x, nullptr, nullptr, nullptr, nullptr,
        w1l, b1l, w1r, hA, ssum1, ssq1);

    // layer 2: 6 -> 8 (stride 8 -> 8), CIL=8 (2 garbage ch, never read), +stats
    layer_kernel<6, 8, 8, 8, 8, true, true><<<NLBLK, 512, 0, stream>>>(
        row_ptr, col, hA, ssum1, ssq1, g1, be1,
        w2l, b2l, w2r, hB, ssum2, ssq2);

    // layer 3: 8 -> 16 (stride 8 -> 16), +stats
    layer_kernel<8, 8, 8, 16, 16, true, true><<<NLBLK, 512, 0, stream>>>(
        row_ptr, col, hB, ssum2, ssq2, g2, be2,
        w3l, b3l, w3r, hA, ssum3, ssq3);

    // layer 4: 16 -> 32 (stride 16 -> 32), ReLU -> d_out
    layer_kernel<16, 16, 16, 32, 32, true, false><<<NLBLK, 512, 0, stream>>>(
        row_ptr, col, hA, ssum3, ssq3, g3, be3,
        w4l, b4l, w4r, (float*)d_out, nullptr, nullptr);
}

// Round 5
// 324.329 us; speedup vs baseline: 1.9950x; 1.6988x over previous
//
#include <hip/hip_runtime.h>

#define NNODES 100000
#define NEDGES 1600000
#define BN_EPS 1e-5f
#define L2_EPS 1e-12f

#define BKT_SHIFT 9
#define BKT_SIZE  512
#define NBKT      196            // ceil(100000/512)
#define CHUNK     8192
#define NBLK_E    196            // ceil(1600000/8192)
#define NSLOT     64             // BN-stats shard count
#define NPB       64             // nodes per layer-block (divides BKT_SIZE)
#define SRCMASK   0x03FFFFFFu    // low 26 bits of packed col = src id

// ---------------------------------------------------------------------------
// Wave-level block exclusive scan (NT threads). Leading barrier protects wsum
// reuse across consecutive calls.
template<int NT>
__device__ __forceinline__ int block_excl_scan(int v, int* wsum) {
    __syncthreads();
    constexpr int NW = NT / 64;
    int incl = v;
#pragma unroll
    for (int off = 1; off < 64; off <<= 1) {
        int t = __shfl_up(incl, off);
        if ((threadIdx.x & 63) >= off) incl += t;
    }
    int wid = threadIdx.x >> 6;
    if ((threadIdx.x & 63) == 63) wsum[wid] = incl;
    __syncthreads();
    if (threadIdx.x < NW) {
        int w = wsum[threadIdx.x];
#pragma unroll
        for (int off = 1; off < NW; off <<= 1) {
            int t = __shfl_up(w, off);
            if ((int)threadIdx.x >= off) w += t;
        }
        wsum[threadIdx.x] = w;             // inclusive wave sums
    }
    __syncthreads();
    int base = wid ? wsum[wid - 1] : 0;
    return base + incl - v;
}

// ---------------------------------------------------------------------------
// Pass 1: per-block bucket histogram (LDS) -> transposed blk_hist. Block 0
// also zeroes the sharded BN stats accumulators.
__global__ void hist_kernel(const int* __restrict__ dst,
                            int* __restrict__ blk_hist_T, float* __restrict__ stats) {
    __shared__ int h[NBKT];
    for (int i = threadIdx.x; i < NBKT; i += blockDim.x) h[i] = 0;
    if (blockIdx.x == 0)
        for (int i = threadIdx.x; i < 3 * NSLOT * 64; i += blockDim.x) stats[i] = 0.0f;
    __syncthreads();
    int base = blockIdx.x * CHUNK;
    int end  = min(base + CHUNK, NEDGES);
    for (int e = base + threadIdx.x * 4; e < end; e += blockDim.x * 4) {
        int4 d = *reinterpret_cast<const int4*>(dst + e);
        atomicAdd(&h[d.x >> BKT_SHIFT], 1);
        atomicAdd(&h[d.y >> BKT_SHIFT], 1);
        atomicAdd(&h[d.z >> BKT_SHIFT], 1);
        atomicAdd(&h[d.w >> BKT_SHIFT], 1);
    }
    __syncthreads();
    for (int i = threadIdx.x; i < NBKT; i += blockDim.x)
        blk_hist_T[i * NBLK_E + blockIdx.x] = h[i];   // [bucket][block]
}

// Per-bucket exclusive scan across blocks + bucket totals as by-product.
__global__ void scan_blocks(const int* __restrict__ blk_hist_T,
                            int* __restrict__ blk_off, int* __restrict__ bucket_total) {
    __shared__ int wsum[4];
    int b = blockIdx.x;
    int i = threadIdx.x;
    int v = (i < NBLK_E) ? blk_hist_T[b * NBLK_E + i] : 0;
    int excl = block_excl_scan<256>(v, wsum);
    if (i < NBLK_E) blk_off[i * NBKT + b] = excl;     // [block][bucket]
    if (i == 255) bucket_total[b] = excl + v;
}

// Pass 2: scatter edges into bucket segments (packed dst_local<<23 | src).
__global__ void bucket_scatter(const int* __restrict__ src, const int* __restrict__ dst,
                               const int* __restrict__ blk_off, const int* __restrict__ bucket_total,
                               unsigned int* __restrict__ staged) {
    __shared__ int cur[NBKT];
    __shared__ int wsum[8];
    int v = (threadIdx.x < NBKT) ? bucket_total[threadIdx.x] : 0;
    int bbase = block_excl_scan<512>(v, wsum);
    if (threadIdx.x < NBKT)
        cur[threadIdx.x] = bbase + blk_off[blockIdx.x * NBKT + threadIdx.x];
    __syncthreads();
    int base = blockIdx.x * CHUNK;
    int end  = min(base + CHUNK, NEDGES);
    for (int e = base + threadIdx.x * 4; e < end; e += blockDim.x * 4) {
        int4 d = *reinterpret_cast<const int4*>(dst + e);
        int4 s = *reinterpret_cast<const int4*>(src + e);
        int p0 = atomicAdd(&cur[d.x >> BKT_SHIFT], 1);
        staged[p0] = ((unsigned)(d.x & (BKT_SIZE - 1)) << 23) | (unsigned)s.x;
        int p1 = atomicAdd(&cur[d.y >> BKT_SHIFT], 1);
        staged[p1] = ((unsigned)(d.y & (BKT_SIZE - 1)) << 23) | (unsigned)s.y;
        int p2 = atomicAdd(&cur[d.z >> BKT_SHIFT], 1);
        staged[p2] = ((unsigned)(d.z & (BKT_SIZE - 1)) << 23) | (unsigned)s.z;
        int p3 = atomicAdd(&cur[d.w >> BKT_SHIFT], 1);
        staged[p3] = ((unsigned)(d.w & (BKT_SIZE - 1)) << 23) | (unsigned)s.w;
    }
}

// Pass 3: one block per bucket -> exact CSR. col entries carry the node-local
// id (within a 64-node layer block) in the top 6 bits: (l & 63) << 26 | src.
__global__ void csr_finalize(const unsigned int* __restrict__ staged,
                             const int* __restrict__ bucket_total,
                             int* __restrict__ row_ptr, unsigned int* __restrict__ col) {
    __shared__ int nh[BKT_SIZE];
    __shared__ int cur[BKT_SIZE];
    __shared__ int wsum[8];
    __shared__ int sBeg, sEnd;
    int b = blockIdx.x;

    nh[threadIdx.x] = 0;                      // covered by scan's leading barrier
    int v = (threadIdx.x < NBKT) ? bucket_total[threadIdx.x] : 0;
    int excl = block_excl_scan<512>(v, wsum);
    if (threadIdx.x == b) { sBeg = excl; sEnd = excl + v; }
    __syncthreads();
    int beg = sBeg, end = sEnd;

    for (int e = beg + threadIdx.x; e < end; e += blockDim.x)
        atomicAdd(&nh[staged[e] >> 23], 1);
    __syncthreads();

    int hv = nh[threadIdx.x];
    int hexcl = block_excl_scan<512>(hv, wsum);

    int node = b * BKT_SIZE + threadIdx.x;
    if (node < NNODES) row_ptr[node] = beg + hexcl;
    if (b == 0 && threadIdx.x == 0) row_ptr[NNODES] = NEDGES;
    cur[threadIdx.x] = hexcl;
    __syncthreads();

    for (int e = beg + threadIdx.x; e < end; e += blockDim.x) {
        unsigned pk = staged[e];
        int l = (int)(pk >> 23);
        int p = atomicAdd(&cur[l], 1);          // LDS atomic only
        col[beg + p] = ((unsigned)(l & (NPB - 1)) << 26) | (pk & 0x7FFFFF);
    }
}

// ---------------------------------------------------------------------------
// Vector row load: float4 chunks, then float2, then scalar.
template<int CI>
__device__ __forceinline__ void load_row(const float* __restrict__ p, float* r) {
    constexpr int N4 = CI / 4;
#pragma unroll
    for (int i = 0; i < N4; i++) {
        float4 v = ((const float4*)p)[i];
        r[4*i] = v.x; r[4*i+1] = v.y; r[4*i+2] = v.z; r[4*i+3] = v.w;
    }
    if constexpr ((CI % 4) >= 2) {
        float2 v = ((const float2*)(p + 4 * N4))[0];
        r[4*N4] = v.x; r[4*N4+1] = v.y;
    }
    if constexpr ((CI % 2) == 1) r[CI - 1] = p[CI - 1];
}

// ---------------------------------------------------------------------------
// Two-phase fused layer, blocked-run edge assignment.
// Phase A: thread = (contiguous edge run, float4 chunk). Lanes executing
//   together sit in DIFFERENT runs -> different dst nodes -> no same-address
//   LDS-atomic serialization (round-4 lesson). Within a run, dst-sorted edges
//   are accumulated in a register float4 and flushed to LDS on dst change
//   (~deg-fold fewer atomics). 2-stage pipeline: col 2-ahead, row 1-ahead.
// Phase B: node-parallel linear + L2 norm + ReLU + BN stats.
// CIL >= CI (multiple of 4): for CI=6 we accumulate 8 channels; the 2 garbage
// channels of the stride-8 rows are never read in Phase B (linearity).
template<int CI, int CIL, int SI, int CO, int SO, bool IN_AFFINE, bool DO_STATS>
__global__ __launch_bounds__(512, 4)
void layer_kernel(const int* __restrict__ row_ptr, const unsigned int* __restrict__ col,
                  const float* __restrict__ h,
                  const float* __restrict__ ssum_in, const float* __restrict__ ssq_in,
                  const float* __restrict__ g_in, const float* __restrict__ b_in,
                  const float* __restrict__ wl, const float* __restrict__ bl,
                  const float* __restrict__ wr,
                  float* __restrict__ y,
                  float* __restrict__ stat_sum, float* __restrict__ stat_sq) {
    constexpr int CIp  = CI + 1;             // padded weight stride
    constexpr int CILp = CIL + 1;            // padded acc stride (odd -> bank spread)
    constexpr int NCH  = CIL / 4;            // float4 chunks per edge
    constexpr int NRUN = 512 / NCH;          // contiguous runs per block
    constexpr int TPN  = 512 / NPB;          // 8 threads per node
    constexpr int OPT  = (CO + TPN - 1) / TPN;

    __shared__ float acc[NPB * CILp];
    __shared__ float sWl[CO * CIp];
    __shared__ float sWr[CO * CIp];
    __shared__ float sBl[CO];
    __shared__ float sSc[CI];
    __shared__ float sSh[CI];
    __shared__ int   sRP[NPB + 1];
    __shared__ float sSumR[CI];
    __shared__ float sSqR[CI];
    __shared__ float red_sum[CO];
    __shared__ float red_sq[CO];

    int tid = threadIdx.x;
    for (int i = tid; i < CO * CI; i += 512) {
        int o = i / CI, c = i - o * CI;
        sWl[o * CIp + c] = wl[i];
        sWr[o * CIp + c] = wr[i];
    }
    if (tid < CO) {
        sBl[tid] = bl[tid];
        if (DO_STATS) { red_sum[tid] = 0.0f; red_sq[tid] = 0.0f; }
    }
    for (int i = tid; i < NPB * CILp; i += 512) acc[i] = 0.0f;
    int first = blockIdx.x * NPB;
    if (tid <= NPB) sRP[tid] = row_ptr[min(first + tid, NNODES)];
    if (IN_AFFINE && tid < CI) { sSumR[tid] = 0.0f; sSqR[tid] = 0.0f; }
    __syncthreads();
    if (IN_AFFINE) {
        int c = tid & 31, sl = tid >> 5;     // 16 slices over NSLOT shards
        if (c < CI) {
            float ps = 0.0f, pq = 0.0f;
#pragma unroll
            for (int s = sl; s < NSLOT; s += 16) {
                ps += ssum_in[s * 64 + c];
                pq += ssq_in[s * 64 + c];
            }
            atomicAdd(&sSumR[c], ps);
            atomicAdd(&sSqR[c], pq);
        }
        __syncthreads();
        if (tid < CI) {
            float m  = sSumR[tid] * (1.0f / NNODES);
            float vv = sSqR[tid] * (1.0f / NNODES) - m * m;
            float s  = g_in[tid] / sqrtf(vv + BN_EPS);
            sSc[tid] = s;
            sSh[tid] = b_in[tid] - m * s;
        }
        __syncthreads();
    }

    // ---- Phase A: blocked-run edge-parallel accumulate ----
    {
        int ebeg = sRP[0], eend = sRP[NPB];
        int M = eend - ebeg;
        int L = (M + NRUN - 1) / NRUN;       // run length
        int run = tid / NCH;
        int ch4 = (tid & (NCH - 1)) * 4;     // my channel chunk
        int s  = ebeg + run * L;
        int se = min(s + L, eend);

        float4 racc = {0.f, 0.f, 0.f, 0.f};
        float4 r0   = {0.f, 0.f, 0.f, 0.f};
        int cur_d = -1;
        unsigned c0 = 0u, c1 = 0u;
        if (s < se)     c0 = col[s];
        if (s + 1 < se) c1 = col[s + 1];
        if (s < se)     r0 = *(const float4*)(h + (long)(c0 & SRCMASK) * SI + ch4);

        for (int e = s; e < se; ++e) {
            unsigned cn = (e + 2 < se) ? col[e + 2] : 0u;          // col 2-ahead
            float4 rn = r0;
            if (e + 1 < se)                                        // row 1-ahead
                rn = *(const float4*)(h + (long)(c1 & SRCMASK) * SI + ch4);
            int d = (int)(c0 >> 26);
            if (d != cur_d) {
                if (cur_d >= 0) {
                    int b = cur_d * CILp + ch4;
                    atomicAdd(&acc[b + 0], racc.x); atomicAdd(&acc[b + 1], racc.y);
                    atomicAdd(&acc[b + 2], racc.z); atomicAdd(&acc[b + 3], racc.w);
                }
                cur_d = d;
                racc = r0;
            } else {
                racc.x += r0.x; racc.y += r0.y; racc.z += r0.z; racc.w += r0.w;
            }
            c0 = c1; c1 = cn; r0 = rn;
        }
        if (cur_d >= 0) {
            int b = cur_d * CILp + ch4;
            atomicAdd(&acc[b + 0], racc.x); atomicAdd(&acc[b + 1], racc.y);
            atomicAdd(&acc[b + 2], racc.z); atomicAdd(&acc[b + 3], racc.w);
        }
    }
    __syncthreads();

    // ---- Phase B: node-parallel epilogue (8 threads per node) ----
    int nl = tid / TPN, t = tid & (TPN - 1);
    int node = first + nl;
    bool valid = node < NNODES;

    float outv[OPT];
    float nrm2 = 0.0f;
    if (valid) {
        int deg = sRP[nl + 1] - sRP[nl];
        float ic = 1.0f / fmaxf((float)deg, 1.0f);
        float a[CI], xin[CI];
        load_row<CI>(h + (long)node * SI, xin);
#pragma unroll
        for (int c = 0; c < CI; c++) {
            float av = acc[nl * CILp + c] * ic;
            float xv = xin[c];
            if (IN_AFFINE) {
                av = av * sSc[c] + sSh[c];
                xv = xv * sSc[c] + sSh[c];
            }
            a[c] = av;
            xin[c] = xv;
        }
#pragma unroll
        for (int k = 0; k < OPT; k++) {
            int o = t * OPT + k;
            float v = 0.0f;
            if (o < CO) {
                v = sBl[o];
#pragma unroll
                for (int c = 0; c < CI; c++)
                    v += sWl[o * CIp + c] * a[c] + sWr[o * CIp + c] * xin[c];
            }
            outv[k] = v;
            nrm2 += v * v;
        }
    }
    nrm2 += __shfl_xor(nrm2, 1);             // 8-lane group = one node
    nrm2 += __shfl_xor(nrm2, 2);
    nrm2 += __shfl_xor(nrm2, 4);

    if (valid) {
        float inv_nrm = 1.0f / fmaxf(sqrtf(nrm2), L2_EPS);
#pragma unroll
        for (int k = 0; k < OPT; k++) {
            int o = t * OPT + k;
            if (o < CO) {
                float v = fmaxf(outv[k] * inv_nrm, 0.0f);   // L2 norm + ReLU
                y[(long)node * SO + o] = v;
                if (DO_STATS) {
                    atomicAdd(&red_sum[o], v);
                    atomicAdd(&red_sq[o], v * v);
                }
            }
        }
    }

    if (DO_STATS) {
        __syncthreads();
        if (tid < CO) {
            int slot = blockIdx.x & (NSLOT - 1);
            atomicAdd(&stat_sum[slot * 64 + tid], red_sum[tid]);
            atomicAdd(&stat_sq [slot * 64 + tid], red_sq[tid]);
        }
    }
}

// ---------------------------------------------------------------------------
extern "C" void kernel_launch(void* const* d_in, const int* in_sizes, int n_in,
                              void* d_out, int out_size, void* d_ws, size_t ws_size,
                              hipStream_t stream) {
    const float* x   = (const float*)d_in[0];
    const int*   ei  = (const int*)d_in[1];
    const int*   src = ei;
    const int*   dst = ei + NEDGES;

    const float* w1l = (const float*)d_in[2];
    const float* b1l = (const float*)d_in[3];
    const float* w1r = (const float*)d_in[4];
    const float* w2l = (const float*)d_in[5];
    const float* b2l = (const float*)d_in[6];
    const float* w2r = (const float*)d_in[7];
    const float* w3l = (const float*)d_in[8];
    const float* b3l = (const float*)d_in[9];
    const float* w3r = (const float*)d_in[10];
    const float* w4l = (const float*)d_in[11];
    const float* b4l = (const float*)d_in[12];
    const float* w4r = (const float*)d_in[13];
    const float* g1  = (const float*)d_in[14];
    const float* be1 = (const float*)d_in[15];
    const float* g2  = (const float*)d_in[16];
    const float* be2 = (const float*)d_in[17];
    const float* g3  = (const float*)d_in[18];
    const float* be3 = (const float*)d_in[19];

    char* w = (char*)d_ws;
    int* blk_hist     = (int*)w;  w += NBLK_E * NBKT * 4;
    int* blk_off      = (int*)w;  w += NBLK_E * NBKT * 4;
    int* bucket_total = (int*)w;  w += 256 * 4;
    int* row_ptr      = (int*)w;  w += (NNODES + 8) * 4;
    unsigned int* col = (unsigned int*)w; w += NEDGES * 4;
    float* hA         = (float*)w; w += NNODES * 16 * 4;
    float* hB         = (float*)w; w += NNODES * 16 * 4;   // aliased by staged
    float* stats      = (float*)w; w += 3 * NSLOT * 64 * 4;
    unsigned int* staged = (unsigned int*)hB;  // dead before hB is written

    float* ssum1 = stats + 0 * NSLOT * 64, *ssq1 = ssum1 + 32;
    float* ssum2 = stats + 1 * NSLOT * 64, *ssq2 = ssum2 + 32;
    float* ssum3 = stats + 2 * NSLOT * 64, *ssq3 = ssum3 + 32;

    // atomic-free CSR build (LDS atomics only), 4 launches
    hist_kernel   <<<NBLK_E, 512, 0, stream>>>(dst, blk_hist, stats);
    scan_blocks   <<<NBKT, 256, 0, stream>>>(blk_hist, blk_off, bucket_total);
    bucket_scatter<<<NBLK_E, 512, 0, stream>>>(src, dst, blk_off, bucket_total, staged);
    csr_finalize  <<<NBKT, 512, 0, stream>>>(staged, bucket_total, row_ptr, col);

    const int NLBLK = (NNODES + NPB - 1) / NPB;   // 1563

    // layer 1: 4 -> 6 (stride 4 -> 8), +stats
    layer_kernel<4, 4, 4, 6, 8, false, true><<<NLBLK, 512, 0, stream>>>(
        row_ptr, col, x, nullptr, nullptr, nullptr, nullptr,
        w1l, b1l, w1r, hA, ssum1, ssq1);

    // layer 2: 6 -> 8 (stride 8 -> 8), CIL=8 (2 garbage ch, never read), +stats
    layer_kernel<6, 8, 8, 8, 8, true, true><<<NLBLK, 512, 0, stream>>>(
        row_ptr, col, hA, ssum1, ssq1, g1, be1,
        w2l, b2l, w2r, hB, ssum2, ssq2);

    // layer 3: 8 -> 16 (stride 8 -> 16), +stats
    layer_kernel<8, 8, 8, 16, 16, true, true><<<NLBLK, 512, 0, stream>>>(
        row_ptr, col, hB, ssum2, ssq2, g2, be2,
        w3l, b3l, w3r, hA, ssum3, ssq3);

    // layer 4: 16 -> 32 (stride 16 -> 32), ReLU -> d_out
    layer_kernel<16, 16, 16, 32, 32, true, false><<<NLBLK, 512, 0, stream>>>(
        row_ptr, col, hA, ssum3, ssq3, g3, be3,
        w4l, b4l, w4r, (float*)d_out, nullptr, nullptr);
}

// Round 6
// 320.744 us; speedup vs baseline: 2.0173x; 1.0112x over previous
//
#include <hip/hip_runtime.h>

#define NNODES 100000
#define NEDGES 1600000
#define BN_EPS 1e-5f
#define L2_EPS 1e-12f

#define BKT_SHIFT 9
#define BKT_SIZE  512
#define NBKT      196            // ceil(100000/512)
#define CHUNK     8192
#define NBLK_E    196            // ceil(1600000/8192)
#define NSLOT     64             // BN-stats shard count
#define NPB       64             // nodes per layer-block (divides BKT_SIZE)
#define SRCMASK   0x03FFFFFFu    // low 26 bits of packed col = src id

// ---------------------------------------------------------------------------
// Wave-level block exclusive scan (NT threads). Leading barrier protects wsum
// reuse across consecutive calls.
template<int NT>
__device__ __forceinline__ int block_excl_scan(int v, int* wsum) {
    __syncthreads();
    constexpr int NW = NT / 64;
    int incl = v;
#pragma unroll
    for (int off = 1; off < 64; off <<= 1) {
        int t = __shfl_up(incl, off);
        if ((threadIdx.x & 63) >= off) incl += t;
    }
    int wid = threadIdx.x >> 6;
    if ((threadIdx.x & 63) == 63) wsum[wid] = incl;
    __syncthreads();
    if (threadIdx.x < NW) {
        int w = wsum[threadIdx.x];
#pragma unroll
        for (int off = 1; off < NW; off <<= 1) {
            int t = __shfl_up(w, off);
            if ((int)threadIdx.x >= off) w += t;
        }
        wsum[threadIdx.x] = w;             // inclusive wave sums
    }
    __syncthreads();
    int base = wid ? wsum[wid - 1] : 0;
    return base + incl - v;
}

// ---------------------------------------------------------------------------
// Pass 1: per-block bucket histogram (LDS) -> transposed blk_hist. Block 0
// also zeroes the sharded BN stats accumulators.
__global__ void hist_kernel(const int* __restrict__ dst,
                            int* __restrict__ blk_hist_T, float* __restrict__ stats) {
    __shared__ int h[NBKT];
    for (int i = threadIdx.x; i < NBKT; i += blockDim.x) h[i] = 0;
    if (blockIdx.x == 0)
        for (int i = threadIdx.x; i < 3 * NSLOT * 64; i += blockDim.x) stats[i] = 0.0f;
    __syncthreads();
    int base = blockIdx.x * CHUNK;
    int end  = min(base + CHUNK, NEDGES);
    for (int e = base + threadIdx.x * 4; e < end; e += blockDim.x * 4) {
        int4 d = *reinterpret_cast<const int4*>(dst + e);
        atomicAdd(&h[d.x >> BKT_SHIFT], 1);
        atomicAdd(&h[d.y >> BKT_SHIFT], 1);
        atomicAdd(&h[d.z >> BKT_SHIFT], 1);
        atomicAdd(&h[d.w >> BKT_SHIFT], 1);
    }
    __syncthreads();
    for (int i = threadIdx.x; i < NBKT; i += blockDim.x)
        blk_hist_T[i * NBLK_E + blockIdx.x] = h[i];   // [bucket][block]
}

// Per-bucket exclusive scan across blocks + bucket totals as by-product.
__global__ void scan_blocks(const int* __restrict__ blk_hist_T,
                            int* __restrict__ blk_off, int* __restrict__ bucket_total) {
    __shared__ int wsum[4];
    int b = blockIdx.x;
    int i = threadIdx.x;
    int v = (i < NBLK_E) ? blk_hist_T[b * NBLK_E + i] : 0;
    int excl = block_excl_scan<256>(v, wsum);
    if (i < NBLK_E) blk_off[i * NBKT + b] = excl;     // [block][bucket]
    if (i == 255) bucket_total[b] = excl + v;
}

// Pass 2: scatter edges into bucket segments (packed dst_local<<23 | src).
__global__ void bucket_scatter(const int* __restrict__ src, const int* __restrict__ dst,
                               const int* __restrict__ blk_off, const int* __restrict__ bucket_total,
                               unsigned int* __restrict__ staged) {
    __shared__ int cur[NBKT];
    __shared__ int wsum[8];
    int v = (threadIdx.x < NBKT) ? bucket_total[threadIdx.x] : 0;
    int bbase = block_excl_scan<512>(v, wsum);
    if (threadIdx.x < NBKT)
        cur[threadIdx.x] = bbase + blk_off[blockIdx.x * NBKT + threadIdx.x];
    __syncthreads();
    int base = blockIdx.x * CHUNK;
    int end  = min(base + CHUNK, NEDGES);
    for (int e = base + threadIdx.x * 4; e < end; e += blockDim.x * 4) {
        int4 d = *reinterpret_cast<const int4*>(dst + e);
        int4 s = *reinterpret_cast<const int4*>(src + e);
        int p0 = atomicAdd(&cur[d.x >> BKT_SHIFT], 1);
        staged[p0] = ((unsigned)(d.x & (BKT_SIZE - 1)) << 23) | (unsigned)s.x;
        int p1 = atomicAdd(&cur[d.y >> BKT_SHIFT], 1);
        staged[p1] = ((unsigned)(d.y & (BKT_SIZE - 1)) << 23) | (unsigned)s.y;
        int p2 = atomicAdd(&cur[d.z >> BKT_SHIFT], 1);
        staged[p2] = ((unsigned)(d.z & (BKT_SIZE - 1)) << 23) | (unsigned)s.z;
        int p3 = atomicAdd(&cur[d.w >> BKT_SHIFT], 1);
        staged[p3] = ((unsigned)(d.w & (BKT_SIZE - 1)) << 23) | (unsigned)s.w;
    }
}

// Pass 3: one block per bucket -> exact CSR. col entries carry the node-local
// id (within a 64-node layer block) in the top 6 bits: (l & 63) << 26 | src.
__global__ void csr_finalize(const unsigned int* __restrict__ staged,
                             const int* __restrict__ bucket_total,
                             int* __restrict__ row_ptr, unsigned int* __restrict__ col) {
    __shared__ int nh[BKT_SIZE];
    __shared__ int cur[BKT_SIZE];
    __shared__ int wsum[8];
    __shared__ int sBeg, sEnd;
    int b = blockIdx.x;

    nh[threadIdx.x] = 0;                      // covered by scan's leading barrier
    int v = (threadIdx.x < NBKT) ? bucket_total[threadIdx.x] : 0;
    int excl = block_excl_scan<512>(v, wsum);
    if (threadIdx.x == b) { sBeg = excl; sEnd = excl + v; }
    __syncthreads();
    int beg = sBeg, end = sEnd;

    for (int e = beg + threadIdx.x; e < end; e += blockDim.x)
        atomicAdd(&nh[staged[e] >> 23], 1);
    __syncthreads();

    int hv = nh[threadIdx.x];
    int hexcl = block_excl_scan<512>(hv, wsum);

    int node = b * BKT_SIZE + threadIdx.x;
    if (node < NNODES) row_ptr[node] = beg + hexcl;
    if (b == 0 && threadIdx.x == 0) row_ptr[NNODES] = NEDGES;
    cur[threadIdx.x] = hexcl;
    __syncthreads();

    for (int e = beg + threadIdx.x; e < end; e += blockDim.x) {
        unsigned pk = staged[e];
        int l = (int)(pk >> 23);
        int p = atomicAdd(&cur[l], 1);          // LDS atomic only
        col[beg + p] = ((unsigned)(l & (NPB - 1)) << 26) | (pk & 0x7FFFFF);
    }
}

// ---------------------------------------------------------------------------
// Vector row load: float4 chunks, then float2, then scalar.
template<int CI>
__device__ __forceinline__ void load_row(const float* __restrict__ p, float* r) {
    constexpr int N4 = CI / 4;
#pragma unroll
    for (int i = 0; i < N4; i++) {
        float4 v = ((const float4*)p)[i];
        r[4*i] = v.x; r[4*i+1] = v.y; r[4*i+2] = v.z; r[4*i+3] = v.w;
    }
    if constexpr ((CI % 4) >= 2) {
        float2 v = ((const float2*)(p + 4 * N4))[0];
        r[4*N4] = v.x; r[4*N4+1] = v.y;
    }
    if constexpr ((CI % 2) == 1) r[CI - 1] = p[CI - 1];
}

// ---------------------------------------------------------------------------
// Two-phase fused layer, blocked-run edge assignment + depth-4 pipeline.
// Phase A: thread = (contiguous edge run, float4 chunk). Lanes executing
//   together sit in DIFFERENT runs -> no same-address LDS-atomic serialization
//   (round-4 lesson). Batches of 4 edges: rows for batch b+1 and cols for
//   batch b+2 are issued before processing batch b -> ~4x fewer serial
//   latency steps per run (round-5 lesson: per-edge latency dominates).
//   Register accumulate with flush-on-dst-change (dst-sorted runs).
// Phase B: node-parallel linear + L2 norm + ReLU + BN stats.
template<int CI, int CIL, int SI, int CO, int SO, bool IN_AFFINE, bool DO_STATS>
__global__ __launch_bounds__(512, 4)
void layer_kernel(const int* __restrict__ row_ptr, const unsigned int* __restrict__ col,
                  const float* __restrict__ h,
                  const float* __restrict__ ssum_in, const float* __restrict__ ssq_in,
                  const float* __restrict__ g_in, const float* __restrict__ b_in,
                  const float* __restrict__ wl, const float* __restrict__ bl,
                  const float* __restrict__ wr,
                  float* __restrict__ y,
                  float* __restrict__ stat_sum, float* __restrict__ stat_sq) {
    constexpr int CIp  = CI + 1;             // padded weight stride
    constexpr int CILp = CIL + 1;            // padded acc stride (odd -> bank spread)
    constexpr int NCH  = CIL / 4;            // float4 chunks per edge
    constexpr int NRUN = 512 / NCH;          // contiguous runs per block
    constexpr int TPN  = 512 / NPB;          // 8 threads per node
    constexpr int OPT  = (CO + TPN - 1) / TPN;

    __shared__ float acc[NPB * CILp];
    __shared__ float sWl[CO * CIp];
    __shared__ float sWr[CO * CIp];
    __shared__ float sBl[CO];
    __shared__ float sSc[CI];
    __shared__ float sSh[CI];
    __shared__ int   sRP[NPB + 1];
    __shared__ float sSumR[CI];
    __shared__ float sSqR[CI];
    __shared__ float red_sum[CO];
    __shared__ float red_sq[CO];

    int tid = threadIdx.x;
    for (int i = tid; i < CO * CI; i += 512) {
        int o = i / CI, c = i - o * CI;
        sWl[o * CIp + c] = wl[i];
        sWr[o * CIp + c] = wr[i];
    }
    if (tid < CO) {
        sBl[tid] = bl[tid];
        if (DO_STATS) { red_sum[tid] = 0.0f; red_sq[tid] = 0.0f; }
    }
    for (int i = tid; i < NPB * CILp; i += 512) acc[i] = 0.0f;
    int first = blockIdx.x * NPB;
    if (tid <= NPB) sRP[tid] = row_ptr[min(first + tid, NNODES)];
    if (IN_AFFINE && tid < CI) { sSumR[tid] = 0.0f; sSqR[tid] = 0.0f; }
    __syncthreads();
    if (IN_AFFINE) {
        int c = tid & 31, sl = tid >> 5;     // 16 slices over NSLOT shards
        if (c < CI) {
            float ps = 0.0f, pq = 0.0f;
#pragma unroll
            for (int s = sl; s < NSLOT; s += 16) {
                ps += ssum_in[s * 64 + c];
                pq += ssq_in[s * 64 + c];
            }
            atomicAdd(&sSumR[c], ps);
            atomicAdd(&sSqR[c], pq);
        }
        __syncthreads();
        if (tid < CI) {
            float m  = sSumR[tid] * (1.0f / NNODES);
            float vv = sSqR[tid] * (1.0f / NNODES) - m * m;
            float s  = g_in[tid] / sqrtf(vv + BN_EPS);
            sSc[tid] = s;
            sSh[tid] = b_in[tid] - m * s;
        }
        __syncthreads();
    }

    // ---- Phase A: blocked-run, depth-4 pipelined accumulate ----
    {
        int ebeg = sRP[0], eend = sRP[NPB];
        int M = eend - ebeg;
        int L = (M + NRUN - 1) / NRUN;       // run length
        int run = tid / NCH;
        int ch4 = (tid & (NCH - 1)) * 4;     // my channel chunk
        int s  = ebeg + run * L;
        int se = min(s + L, eend);

#define ROWLD(c) (*(const float4*)(h + (long)((c) & SRCMASK) * SI + ch4))

        float4 racc = {0.f, 0.f, 0.f, 0.f};
        int cur_d = -1;

        // batch A (current), batch B cols (next)
        unsigned cA0 = (s     < se) ? col[s]     : 0u;
        unsigned cA1 = (s + 1 < se) ? col[s + 1] : 0u;
        unsigned cA2 = (s + 2 < se) ? col[s + 2] : 0u;
        unsigned cA3 = (s + 3 < se) ? col[s + 3] : 0u;
        float4 rA0 = ROWLD(cA0);
        float4 rA1 = ROWLD(cA1);
        float4 rA2 = ROWLD(cA2);
        float4 rA3 = ROWLD(cA3);
        unsigned cB0 = (s + 4 < se) ? col[s + 4] : 0u;
        unsigned cB1 = (s + 5 < se) ? col[s + 5] : 0u;
        unsigned cB2 = (s + 6 < se) ? col[s + 6] : 0u;
        unsigned cB3 = (s + 7 < se) ? col[s + 7] : 0u;

        for (int b = s; b < se; b += 4) {
            // issue next-batch rows (from cB) and batch-after-next cols
            float4 rB0 = ROWLD(cB0);
            float4 rB1 = ROWLD(cB1);
            float4 rB2 = ROWLD(cB2);
            float4 rB3 = ROWLD(cB3);
            unsigned cC0 = (b + 8  < se) ? col[b + 8]  : 0u;
            unsigned cC1 = (b + 9  < se) ? col[b + 9]  : 0u;
            unsigned cC2 = (b + 10 < se) ? col[b + 10] : 0u;
            unsigned cC3 = (b + 11 < se) ? col[b + 11] : 0u;

            // process current batch (flush-on-dst-change)
#define PROC(i, cc, rr)                                                      \
            if (b + i < se) {                                                \
                int d_ = (int)((cc) >> 26);                                  \
                if (d_ != cur_d) {                                           \
                    if (cur_d >= 0) {                                        \
                        int a_ = cur_d * CILp + ch4;                         \
                        atomicAdd(&acc[a_ + 0], racc.x);                     \
                        atomicAdd(&acc[a_ + 1], racc.y);                     \
                        atomicAdd(&acc[a_ + 2], racc.z);                     \
                        atomicAdd(&acc[a_ + 3], racc.w);                     \
                    }                                                        \
                    cur_d = d_;                                              \
                    racc = rr;                                               \
                } else {                                                     \
                    racc.x += rr.x; racc.y += rr.y;                          \
                    racc.z += rr.z; racc.w += rr.w;                          \
                }                                                            \
            }
            PROC(0, cA0, rA0)
            PROC(1, cA1, rA1)
            PROC(2, cA2, rA2)
            PROC(3, cA3, rA3)
#undef PROC
            cA0 = cB0; cA1 = cB1; cA2 = cB2; cA3 = cB3;
            cB0 = cC0; cB1 = cC1; cB2 = cC2; cB3 = cC3;
            rA0 = rB0; rA1 = rB1; rA2 = rB2; rA3 = rB3;
        }
        if (cur_d >= 0) {
            int a_ = cur_d * CILp + ch4;
            atomicAdd(&acc[a_ + 0], racc.x);
            atomicAdd(&acc[a_ + 1], racc.y);
            atomicAdd(&acc[a_ + 2], racc.z);
            atomicAdd(&acc[a_ + 3], racc.w);
        }
#undef ROWLD
    }
    __syncthreads();

    // ---- Phase B: node-parallel epilogue (8 threads per node) ----
    int nl = tid / TPN, t = tid & (TPN - 1);
    int node = first + nl;
    bool valid = node < NNODES;

    float outv[OPT];
    float nrm2 = 0.0f;
    if (valid) {
        int deg = sRP[nl + 1] - sRP[nl];
        float ic = 1.0f / fmaxf((float)deg, 1.0f);
        float a[CI], xin[CI];
        load_row<CI>(h + (long)node * SI, xin);
#pragma unroll
        for (int c = 0; c < CI; c++) {
            float av = acc[nl * CILp + c] * ic;
            float xv = xin[c];
            if (IN_AFFINE) {
                av = av * sSc[c] + sSh[c];
                xv = xv * sSc[c] + sSh[c];
            }
            a[c] = av;
            xin[c] = xv;
        }
#pragma unroll
        for (int k = 0; k < OPT; k++) {
            int o = t * OPT + k;
            float v = 0.0f;
            if (o < CO) {
                v = sBl[o];
#pragma unroll
                for (int c = 0; c < CI; c++)
                    v += sWl[o * CIp + c] * a[c] + sWr[o * CIp + c] * xin[c];
            }
            outv[k] = v;
            nrm2 += v * v;
        }
    }
    nrm2 += __shfl_xor(nrm2, 1);             // 8-lane group = one node
    nrm2 += __shfl_xor(nrm2, 2);
    nrm2 += __shfl_xor(nrm2, 4);

    if (valid) {
        float inv_nrm = 1.0f / fmaxf(sqrtf(nrm2), L2_EPS);
#pragma unroll
        for (int k = 0; k < OPT; k++) {
            int o = t * OPT + k;
            if (o < CO) {
                float v = fmaxf(outv[k] * inv_nrm, 0.0f);   // L2 norm + ReLU
                y[(long)node * SO + o] = v;
                if (DO_STATS) {
                    atomicAdd(&red_sum[o], v);
                    atomicAdd(&red_sq[o], v * v);
                }
            }
        }
    }

    if (DO_STATS) {
        __syncthreads();
        if (tid < CO) {
            int slot = blockIdx.x & (NSLOT - 1);
            atomicAdd(&stat_sum[slot * 64 + tid], red_sum[tid]);
            atomicAdd(&stat_sq [slot * 64 + tid], red_sq[tid]);
        }
    }
}

// ---------------------------------------------------------------------------
extern "C" void kernel_launch(void* const* d_in, const int* in_sizes, int n_in,
                              void* d_out, int out_size, void* d_ws, size_t ws_size,
                              hipStream_t stream) {
    const float* x   = (const float*)d_in[0];
    const int*   ei  = (const int*)d_in[1];
    const int*   src = ei;
    const int*   dst = ei + NEDGES;

    const float* w1l = (const float*)d_in[2];
    const float* b1l = (const float*)d_in[3];
    const float* w1r = (const float*)d_in[4];
    const float* w2l = (const float*)d_in[5];
    const float* b2l = (const float*)d_in[6];
    const float* w2r = (const float*)d_in[7];
    const float* w3l = (const float*)d_in[8];
    const float* b3l = (const float*)d_in[9];
    const float* w3r = (const float*)d_in[10];
    const float* w4l = (const float*)d_in[11];
    const float* b4l = (const float*)d_in[12];
    const float* w4r = (const float*)d_in[13];
    const float* g1  = (const float*)d_in[14];
    const float* be1 = (const float*)d_in[15];
    const float* g2  = (const float*)d_in[16];
    const float* be2 = (const float*)d_in[17];
    const float* g3  = (const float*)d_in[18];
    const float* be3 = (const float*)d_in[19];

    char* w = (char*)d_ws;
    int* blk_hist     = (int*)w;  w += NBLK_E * NBKT * 4;
    int* blk_off      = (int*)w;  w += NBLK_E * NBKT * 4;
    int* bucket_total = (int*)w;  w += 256 * 4;
    int* row_ptr      = (int*)w;  w += (NNODES + 8) * 4;
    unsigned int* col = (unsigned int*)w; w += NEDGES * 4;
    float* hA         = (float*)w; w += NNODES * 16 * 4;
    float* hB         = (float*)w; w += NNODES * 16 * 4;   // aliased by staged
    float* stats      = (float*)w; w += 3 * NSLOT * 64 * 4;
    unsigned int* staged = (unsigned int*)hB;  // dead before hB is written

    float* ssum1 = stats + 0 * NSLOT * 64, *ssq1 = ssum1 + 32;
    float* ssum2 = stats + 1 * NSLOT * 64, *ssq2 = ssum2 + 32;
    float* ssum3 = stats + 2 * NSLOT * 64, *ssq3 = ssum3 + 32;

    // atomic-free CSR build (LDS atomics only), 4 launches
    hist_kernel   <<<NBLK_E, 512, 0, stream>>>(dst, blk_hist, stats);
    scan_blocks   <<<NBKT, 256, 0, stream>>>(blk_hist, blk_off, bucket_total);
    bucket_scatter<<<NBLK_E, 512, 0, stream>>>(src, dst, blk_off, bucket_total, staged);
    csr_finalize  <<<NBKT, 512, 0, stream>>>(staged, bucket_total, row_ptr, col);

    const int NLBLK = (NNODES + NPB - 1) / NPB;   // 1563

    // layer 1: 4 -> 6 (stride 4 -> 8), +stats
    layer_kernel<4, 4, 4, 6, 8, false, true><<<NLBLK, 512, 0, stream>>>(
        row_ptr, col, x, nullptr, nullptr, nullptr, nullptr,
        w1l, b1l, w1r, hA, ssum1, ssq1);

    // layer 2: 6 -> 8 (stride 8 -> 8), CIL=8 (2 garbage ch, never read), +stats
    layer_kernel<6, 8, 8, 8, 8, true, true><<<NLBLK, 512, 0, stream>>>(
        row_ptr, col, hA, ssum1, ssq1, g1, be1,
        w2l, b2l, w2r, hB, ssum2, ssq2);

    // layer 3: 8 -> 16 (stride 8 -> 16), +stats
    layer_kernel<8, 8, 8, 16, 16, true, true><<<NLBLK, 512, 0, stream>>>(
        row_ptr, col, hB, ssum2, ssq2, g2, be2,
        w3l, b3l, w3r, hA, ssum3, ssq3);

    // layer 4: 16 -> 32 (stride 16 -> 32), ReLU -> d_out
    layer_kernel<16, 16, 16, 32, 32, true, false><<<NLBLK, 512, 0, stream>>>(
        row_ptr, col, hA, ssum3, ssq3, g3, be3,
        w4l, b4l, w4r, (float*)d_out, nullptr, nullptr);
}